// Round 4
// baseline (291.586 us; speedup 1.0000x reference)
//
#include <hip/hip_runtime.h>

typedef unsigned short u16;
typedef __attribute__((ext_vector_type(8))) short s16x8;   // 8 x bf16 frag (verified form)
typedef __attribute__((ext_vector_type(4))) float floatx4;

// xt (per batch): [cg=16][row=66][col=66][c32=32] bf16, spatial-padded NCHW32c
// SWIZZLED: within each 64B (row,col) channel-group, c32 index ^= ((col>>1)&3)<<3
#define XT_ROWELEMS 2112                 // 66*32
#define XT_CGELEMS  139392               // 66*66*32
#define XT_PB       4460544ull           // 16*66*66*32*2 bytes per batch
// wmod (per batch): [t=9][cg=16][o512=512][c32=32] bf16  (o512 contiguous for M=256 tiles)
// SWIZZLED: within each 64B o-row, c32 index ^= ((o>>1)&3)<<3
#define WM_ELEMS    2359296ull           // 9*16*512*32 elems per batch
#define WM_PB       4718592ull           // bytes per batch

// async global->LDS DMA, 16B per lane; lds dest = wave-uniform base + lane*16
#define GLDS(gp, lp) __builtin_amdgcn_global_load_lds(                      \
    (const __attribute__((address_space(1))) void*)(gp),                    \
    (__attribute__((address_space(3))) void*)(lp), 16, 0, 0)

// counted vmcnt with compiler memory fence (prevents ds_read hoisting above)
#define WAITVM(N) asm volatile("s_waitcnt vmcnt(" #N ")" ::: "memory")

__device__ __forceinline__ u16 f2bf(float f) {
  union { float f; unsigned u; } x; x.f = f;
  unsigned r = x.u + 0x7fffu + ((x.u >> 16) & 1u);
  return (u16)(r >> 16);
}

// ---------------- fused producer: transpose + modulate in one dispatch ----------------
// (unchanged from round 3 — control group)
__global__ __launch_bounds__(256) void prep_fused(
    const float* __restrict__ fm, const float* __restrict__ w,
    const float* __restrict__ style, u16* __restrict__ xt,
    u16* __restrict__ wm, int b0)
{
  __shared__ __align__(16) char smraw[18448];     // union: 64*33 f32 | 4608+4 f32
  const int bid = blockIdx.x;
  const int g = bid / 3, rrole = bid - g * 3;
  const int tid = threadIdx.x;

  if (rrole < 2) {
    float* sm = (float*)smraw;                    // 64*33 floats
    const int ti = g * 2 + rrole;
    const int y = ti & 63, cg = (ti >> 6) & 15, bl = ti >> 10;
    const int x = tid & 63, cq = tid >> 6;
    const float* src = fm + (((size_t)(b0 + bl) * 512 + cg * 32) * 64 + y) * 64;
#pragma unroll
    for (int j = 0; j < 8; ++j) {
      int ci = j * 4 + cq;
      sm[x * 33 + ci] = src[(size_t)ci * 4096 + x];   // coalesced along x
    }

    u16* cgbase = xt + (size_t)(bl * 16 + cg) * XT_CGELEMS;
    const uint4 z = {0u, 0u, 0u, 0u};
    u16* rowb = cgbase + (size_t)(y + 1) * XT_ROWELEMS;
    if (tid < 4)              ((uint4*)rowb)[tid] = z;                  // col 0
    else if (tid < 8)         ((uint4*)(rowb + 65 * 32))[tid - 4] = z;  // col 65
    if (y == 0)  for (int i = tid; i < 264; i += 256) ((uint4*)cgbase)[i] = z;
    if (y == 63) for (int i = tid; i < 264; i += 256) ((uint4*)(cgbase + 65 * XT_ROWELEMS))[i] = z;

    __syncthreads();
    union { u16 s[8]; uint4 v; } u;
#pragma unroll
    for (int j = 0; j < 8; ++j) {
      int e = tid * 8 + j;                            // e = x*32 + c32
      u.s[j] = f2bf(sm[(e >> 5) * 33 + (e & 31)]);
    }
    const int col = 1 + (tid >> 2);
    const int slot = (tid & 3) ^ ((col >> 1) & 3);
    ((uint4*)rowb)[col * 4 + slot] = u.v;
  } else {
    float* sv = (float*)smraw;                    // 4608 floats
    float* red = (float*)(smraw + 18432);         // 4 floats
    const int o = g & 511, bl = g >> 9;
    const float gain = 0.014731391f;              // 1/sqrt(512*9)
    const float* wo = w + (size_t)o * 4608;       // flat idx = ci*9 + t
    const float* st = style + (size_t)(b0 + bl) * 512;
    float ss = 0.f;
#pragma unroll
    for (int j = 0; j < 18; ++j) {
      int idx = j * 256 + tid;
      float v = wo[idx] * gain * st[idx / 9];
      sv[idx] = v;
      ss += v * v;
    }
#pragma unroll
    for (int off = 32; off > 0; off >>= 1) ss += __shfl_down(ss, off, 64);
    if ((tid & 63) == 0) red[tid >> 6] = ss;
    __syncthreads();
    float sinv = rsqrtf(red[0] + red[1] + red[2] + red[3] + 1e-8f);
    const int axor = ((o >> 1) & 3) << 3;         // pre-swizzle for conv A-reads
    u16* base = wm + (size_t)bl * WM_ELEMS + (size_t)o * 32;
#pragma unroll
    for (int j = 0; j < 18; ++j) {
      int e = j * 256 + tid;                      // e = t*512 + c
      int t = e >> 9, c = e & 511;
      base[((size_t)(t * 16 + (c >> 5))) * 16384 + ((c & 31) ^ axor)] = f2bf(sv[c * 9 + t] * sinv);
    }
  }
}

// ---------------- kernel 3: implicit-GEMM conv, m201-style 8-wave phase schedule ----------------
// 256x256 C tile, 512 threads = 8 waves (2M x 4N), per-wave 128x64 (m201 geometry).
// Per K-step (c32 slice): 4 phases {2 ds_read ∥ 1 GLDS -> barrier -> lgkmcnt(0) ->
// setprio(1) -> 8 MFMA -> setprio(0) -> barrier}. A tri-buffered depth-2 prefetch;
// B double-buffered, 4 loads spread over t=3..6. One counted vmcnt per step
// (N from exact per-wave FIFO; all waves issue identical load counts). Loads stay
// in flight across barriers — never drain to 0 in steady state (T3+T4+T5).
__global__ __launch_bounds__(512, 2) void conv_mfma(
    const u16* __restrict__ Wmod, const u16* __restrict__ xt,
    float* __restrict__ out, int b0, int nb)
{
  const int id = blockIdx.x;
  const int bl = id % nb;                           // batch -> XCD (round-robin dispatch)
  const int rest = id / nb;                         // 0..31
  const int og = rest & 1, p_blk = rest >> 1;       // og: 256-row M half; p_blk: 256-px tile
  const int tid = threadIdx.x;
  const int lane = tid & 63, wave = tid >> 6;       // 8 waves
  const int wm_off = (wave & 1) * 128, wn_off = (wave >> 1) * 64;
  const int l15 = lane & 15, quad = lane >> 4;

  __shared__ __align__(16) u16 As[3][8192];         // 3 x 16 KB A k-slices (256 rows x 32)
  __shared__ __align__(16) u16 Bs[2][12672];        // 2 x [r6][col66][c32] = 2 x 25344 B

  const int y0 = p_blk * 4;                         // 4 pixel-rows + 2 halo = 6 xt rows
  const size_t xt_base = ((size_t)(bl * 16) * XT_CGELEMS) + (size_t)y0 * XT_ROWELEMS;
  const size_t w_base = (size_t)bl * WM_ELEMS + (size_t)og * (256 * 32);

  // B stage: 25344 B contiguous = 1584 16B-slots; wave w owns slots [w*198, w*198+198):
  // 3 full GLDS + 1 partial (6 lanes). Every wave issues 4 -> equal vmcnt counts.
  auto stage_b = [&](int cg, int half, int k) {
    const char* g = (const char*)(xt + xt_base + (size_t)cg * XT_CGELEMS);
    char* l = (char*)Bs[half];
    const int off = wave * 3168 + k * 1024;         // 198*16 = 3168
    if (k < 3)            GLDS(g + off + lane * 16, l + off);
    else if (lane < 6)    GLDS(g + off + lane * 16, l + off);
  };
  // A stage: 16 KB contiguous; 2 GLDS/wave (k = 0,1), 8 waves x 1024 B each.
  auto stage_a = [&](int t, int cg, int buf, int k) {
    const char* g = (const char*)(Wmod + w_base + (size_t)(t * 16 + cg) * 16384);
    const int off = k * 8192 + wave * 1024;
    GLDS(g + off + lane * 16, (char*)As[buf] + off);
  };

  // loop-invariant swizzled fragment addresses (verified rounds 1-3, conflicts = 0)
  int aoff[8];
#pragma unroll
  for (int mt = 0; mt < 8; ++mt) {
    int row = wm_off + mt * 16 + l15;
    aoff[mt] = row * 32 + ((quad ^ ((row >> 1) & 3)) << 3);
  }
  int pr[4], pc[4];
#pragma unroll
  for (int nt = 0; nt < 4; ++nt) {
    int p = wn_off + nt * 16 + l15;                 // 0..255
    pr[nt] = p >> 6; pc[nt] = p & 63;
  }

  floatx4 acc[8][4];
  const floatx4 zf = {0.f, 0.f, 0.f, 0.f};
#pragma unroll
  for (int mt = 0; mt < 8; ++mt)
#pragma unroll
    for (int nt = 0; nt < 4; ++nt) acc[mt][nt] = zf;

#define MFMA_PAIR(M0, A0, A1)                                                  \
  _Pragma("unroll")                                                            \
  for (int nt = 0; nt < 4; ++nt) {                                             \
    acc[M0][nt] = __builtin_amdgcn_mfma_f32_16x16x32_bf16(A0, bfr[nt],         \
                                                          acc[M0][nt], 0, 0, 0); \
    acc[M0 + 1][nt] = __builtin_amdgcn_mfma_f32_16x16x32_bf16(A1, bfr[nt],     \
                                                          acc[M0 + 1][nt], 0, 0, 0); \
  }

// one phase: 2 afr ds_reads + optional stage issue; barrier; wait LDS; prio-MFMA; barrier
#define PHASE(M0, I0, I1, STAGE_STMT)                                          \
  {                                                                            \
    s16x8 a0 = *(const s16x8*)&Acur[aoff[I0]];                                 \
    s16x8 a1 = *(const s16x8*)&Acur[aoff[I1]];                                 \
    STAGE_STMT;                                                                \
    __builtin_amdgcn_s_barrier();                                              \
    asm volatile("s_waitcnt lgkmcnt(0)");                                      \
    __builtin_amdgcn_sched_barrier(0);                                         \
    __builtin_amdgcn_s_setprio(1);                                             \
    MFMA_PAIR(M0, a0, a1);                                                     \
    __builtin_amdgcn_s_setprio(0);                                             \
    __builtin_amdgcn_s_barrier();                                              \
  }
// last phase of a step: closing barrier replaced by counted vmcnt + barrier
#define PHASE_END(M0, I0, I1, VMSTMT)                                          \
  {                                                                            \
    s16x8 a0 = *(const s16x8*)&Acur[aoff[I0]];                                 \
    s16x8 a1 = *(const s16x8*)&Acur[aoff[I1]];                                 \
    __builtin_amdgcn_s_barrier();                                              \
    asm volatile("s_waitcnt lgkmcnt(0)");                                      \
    __builtin_amdgcn_sched_barrier(0);                                         \
    __builtin_amdgcn_s_setprio(1);                                             \
    MFMA_PAIR(M0, a0, a1);                                                     \
    __builtin_amdgcn_s_setprio(0);                                             \
    VMSTMT;                                                                    \
    __builtin_amdgcn_s_barrier();                                              \
  }

  // prologue: B(0) [4 loads] + A(0) [2] + A(1) [2]; wait leaves A(1) in flight
  stage_b(0, 0, 0); stage_b(0, 0, 1); stage_b(0, 0, 2); stage_b(0, 0, 3);
  stage_a(0, 0, 0, 0); stage_a(0, 0, 0, 1);
  stage_a(1, 0, 1, 0); stage_a(1, 0, 1, 1);
  WAITVM(2);
  __builtin_amdgcn_s_barrier();

#pragma unroll 1
  for (int cg = 0; cg < 15; ++cg) {
    const int cgp = cg & 1, cgn = cgp ^ 1;
    const u16* Bcur = Bs[cgp];
#pragma unroll
    for (int t = 0; t < 9; ++t) {
      const int cur = t % 3, nx2 = (t + 2) % 3;     // s%3 == t%3 (9 ≡ 0 mod 3)
      const int t2 = (t + 2 < 9) ? t + 2 : t - 7;   // step s+2 coords
      const int cg2 = (t + 2 < 9) ? cg : cg + 1;
      const int ky = t / 3, kx = t - ky * 3;
      const u16* Acur = As[cur];

      s16x8 bfr[4];
#pragma unroll
      for (int nt = 0; nt < 4; ++nt) {              // B[n][k], swizzled (conflict-free)
        int r = pr[nt] + ky, c = pc[nt] + kx;
        bfr[nt] = *(const s16x8*)&Bcur[(r * 66 + c) * 32 + ((quad ^ ((c >> 1) & 3)) << 3)];
      }
      PHASE(0, 0, 1, stage_a(t2, cg2, nx2, 0));     // ph0 (+A(s+2)#0)
      PHASE(2, 2, 3, stage_a(t2, cg2, nx2, 1));     // ph1 (+A(s+2)#1)
      PHASE(4, 4, 5, if (t >= 3 && t <= 6) stage_b(cg + 1, cgn, t - 3));  // ph2 (+B)
      // end-of-step: wait A(s+1) landed; N = loads issued after it (exact FIFO):
      if (t == 3)                 { PHASE_END(6, 6, 7, WAITVM(3)); }
      else if (t >= 4 && t <= 6)  { PHASE_END(6, 6, 7, WAITVM(4)); }
      else                        { PHASE_END(6, 6, 7, WAITVM(2)); }
    }
  }
  { // tail cg = 15: no B staging; A staging while s+2 <= 143 (t <= 6)
    const u16* Bcur = Bs[15 & 1];
#pragma unroll
    for (int t = 0; t < 9; ++t) {
      const int cur = t % 3, nx2 = (t + 2) % 3;
      const int ky = t / 3, kx = t - ky * 3;
      const u16* Acur = As[cur];
      s16x8 bfr[4];
#pragma unroll
      for (int nt = 0; nt < 4; ++nt) {
        int r = pr[nt] + ky, c = pc[nt] + kx;
        bfr[nt] = *(const s16x8*)&Bcur[(r * 66 + c) * 32 + ((quad ^ ((c >> 1) & 3)) << 3)];
      }
      PHASE(0, 0, 1, if (t <= 6) stage_a(t + 2, 15, nx2, 0));
      PHASE(2, 2, 3, if (t <= 6) stage_a(t + 2, 15, nx2, 1));
      PHASE(4, 4, 5, );
      if (t <= 6)       { PHASE_END(6, 6, 7, WAITVM(2)); }
      else if (t == 7)  { PHASE_END(6, 6, 7, WAITVM(0)); }
      else              { PHASE_END(6, 6, 7, ); }
    }
  }
#undef PHASE
#undef PHASE_END
#undef MFMA_PAIR

  // epilogue: C/D layout col=lane&15, row=quad*4+reg (m89-verified)
  float* outp = out + ((size_t)(b0 + bl) * 512 + og * 256) * 4096 + p_blk * 256;
#pragma unroll
  for (int mt = 0; mt < 8; ++mt)
#pragma unroll
    for (int nt = 0; nt < 4; ++nt) {
      int n = wn_off + nt * 16 + l15;
#pragma unroll
      for (int r = 0; r < 4; ++r) {
        int m = wm_off + mt * 16 + quad * 4 + r;
        outp[(size_t)m * 4096 + n] = acc[mt][nt][r];
      }
    }
}

// ---------------- fallback: zero-workspace direct conv (R6, known-PASS) ----------------
__global__ __launch_bounds__(256) void conv_direct(
    const float* __restrict__ fm, const float* __restrict__ style,
    const float* __restrict__ w, float* __restrict__ out)
{
  const int o = blockIdx.x, b = blockIdx.y, tid = threadIdx.x;
  __shared__ float swm[4608];
  __shared__ float red[4];
  const float gain = 0.014731391f;
  const float* wo = w + (size_t)o * 4608;
  const float* st = style + (size_t)b * 512;
  float ss = 0.f;
#pragma unroll
  for (int j = 0; j < 18; ++j) {
    int idx = j * 256 + tid;
    float v = wo[idx] * gain * st[idx / 9];
    swm[idx] = v;
    ss += v * v;
  }
#pragma unroll
  for (int off = 32; off > 0; off >>= 1) ss += __shfl_down(ss, off, 64);
  if ((tid & 63) == 0) red[tid >> 6] = ss;
  __syncthreads();
  const float sinv = rsqrtf(red[0] + red[1] + red[2] + red[3] + 1e-8f);

  const int y = tid >> 2, x0 = (tid & 3) * 16;
  float acc[16];
#pragma unroll
  for (int i = 0; i < 16; ++i) acc[i] = 0.f;
  const float* fb = fm + (size_t)b * 512 * 4096;
  for (int ci = 0; ci < 512; ++ci) {
    const float* fc = fb + (size_t)ci * 4096;
    const float* wr = swm + ci * 9;
#pragma unroll
    for (int ky = 0; ky < 3; ++ky) {
      int yy = y + ky - 1;
      if (yy < 0 || yy > 63) continue;
      const float* frow = fc + yy * 64;
#pragma unroll
      for (int kx = 0; kx < 3; ++kx) {
        float wv = wr[ky * 3 + kx];
#pragma unroll
        for (int i = 0; i < 16; ++i) {
          int xx = x0 + i + kx - 1;
          float xv = (xx >= 0 && xx < 64) ? frow[xx] : 0.f;
          acc[i] += wv * xv;
        }
      }
    }
  }
  float* op = out + ((size_t)b * 512 + o) * 4096 + y * 64 + x0;
#pragma unroll
  for (int i = 0; i < 16; ++i) op[i] = acc[i] * sinv;
}

extern "C" void kernel_launch(void* const* d_in, const int* in_sizes, int n_in,
                              void* d_out, int out_size, void* d_ws, size_t ws_size,
                              hipStream_t stream) {
  const float* fm = (const float*)d_in[0];     // (8,512,64,64) fp32
  const float* style = (const float*)d_in[1];  // (8,512) fp32
  const float* w = (const float*)d_in[2];      // (512,512,3,3) fp32
  float* out = (float*)d_out;                  // (8,512,64,64) fp32

  if (ws_size < XT_PB + WM_PB) {               // workspace too small: direct path
    conv_direct<<<dim3(512, 8), 256, 0, stream>>>(fm, style, w, out);
    return;
  }
  int nb = 8;
  while (nb > 1 && (size_t)nb * (XT_PB + WM_PB) > ws_size) nb >>= 1;

  u16* xt = (u16*)d_ws;
  u16* wmod = (u16*)((char*)d_ws + (size_t)nb * XT_PB);

  for (int b0 = 0; b0 < 8; b0 += nb) {
    prep_fused<<<dim3(1536 * nb), 256, 0, stream>>>(fm, w, style, xt, wmod, b0);
    conv_mfma<<<dim3(32 * nb), 512, 0, stream>>>(wmod, xt, out, b0, nb);
  }
}